// Round 12
// baseline (8280.304 us; speedup 1.0000x reference)
//
#include <hip/hip_runtime.h>

#define IMH 64
#define IMW 64
#define HWSZ 4096
#define BATCH 16
#define TSTEPS 16
#define PADW 66

typedef _Float16 half8 __attribute__((ext_vector_type(8)));
typedef _Float16 half4 __attribute__((ext_vector_type(4)));
typedef float floatx4 __attribute__((ext_vector_type(4)));
typedef int intx4 __attribute__((ext_vector_type(4)));

__device__ __forceinline__ float sigmoidf_(float x) { return 1.f / (1.f + __expf(-x)); }
__device__ __forceinline__ float tanhf_(float x) { return 1.f - 2.f / (1.f + __expf(2.f * x)); }

// layer1 weights: 36 slabs wr[gt][m][k32]; m=(g*4+hg)*16+i -> out=g*64+hg*16+i; ci=chunk*32+k.
__global__ void repack_w1(const float* __restrict__ w, _Float16* __restrict__ wr) {
    int total = 36 * 8192;
    for (int idx = blockIdx.x * blockDim.x + threadIdx.x; idx < total;
         idx += gridDim.x * blockDim.x) {
        int k = idx & 31;
        int m = (idx >> 5) & 255;
        int gt = idx >> 13;
        int chunk = gt / 9, tap = gt - chunk * 9;
        int g = m >> 6, hg = (m >> 4) & 3, i = m & 15;
        int out = g * 64 + hg * 16 + i;
        int ci = chunk * 32 + k;
        wr[idx] = (_Float16)w[(out * 128 + ci) * 9 + tap];
    }
}

// layer0 weights: 18 h-slabs (ci = chunk*32+k+1) + 1 x-slab (K-dim = tap: A[m][k]=w_x[out][k], k<9).
__global__ void repack_w0(const float* __restrict__ w, _Float16* __restrict__ wr) {
    int total = 19 * 8192;
    for (int idx = blockIdx.x * blockDim.x + threadIdx.x; idx < total;
         idx += gridDim.x * blockDim.x) {
        int k = idx & 31;
        int m = (idx >> 5) & 255;
        int gt = idx >> 13;
        int g = m >> 6, hg = (m >> 4) & 3, i = m & 15;
        int out = g * 64 + hg * 16 + i;
        float v = 0.f;
        if (gt < 18) {
            int chunk = gt / 9, tap = gt - chunk * 9;
            v = w[(out * 65 + (chunk * 32 + k + 1)) * 9 + tap];
        } else if (k < 9) {
            v = w[(out * 65 + 0) * 9 + k];   // x-plane, tap k
        }
        wr[idx] = (_Float16)v;
    }
}

// ---- 512-thr block: 8 waves = 4 hid-groups x 2 rows; wave tile M=64 x N=64 ----

// stage 4 halo rows x 66 cols x 32 ch -> 1056 16B units; 5-slot (80B) pixel stride
__device__ __forceinline__ void stage_h(const _Float16* __restrict__ buf, int halfsel,
                                        _Float16* __restrict__ act, int tid, int b, int rb) {
    for (int t = tid; t < 1056; t += 512) {
        int pix = t >> 2, sl = t & 3;
        int r = pix / 66, cs = pix - r * 66;
        const _Float16* g = buf
            + ((size_t)(b * PADW + rb * 2 + r) * PADW + cs) * 64 + halfsel * 32 + sl * 8;
        *(intx4*)&act[(pix * 5 + sl) * 8] = *(const intx4*)g;
    }
}

// NH = number of 32-ch h chunks; XS = append single x-slab (taps in K-dim)
template<int NH, bool XS>
__device__ __forceinline__ void lstm_body(
    const _Float16* __restrict__ srcA,    // h chunks 0-1
    const _Float16* __restrict__ srcB,    // h chunks 2-3
    const float* __restrict__ xsrc,       // layer0 x_t
    _Float16* __restrict__ hpad,          // out h [B][66][66][64]
    float* __restrict__ cpix,             // in-place c [B][4096][64]
    const _Float16* __restrict__ wr,      // [NH*9(+1)][256][32]
    const float* __restrict__ bias,       // [256]
    _Float16* __restrict__ act,           // LDS, 264*5*8 halves (21.1 KB)
    int tid, int rb, int b)
{
    const int lane = tid & 63;
    const int n = lane & 15, q = lane >> 4;
    const int wv = tid >> 6;
    const int hg = wv & 3;                   // hid group
    const int rowsel = wv >> 2;              // 0,1: image row rb*2+rowsel

    floatx4 acc[4][4];
    #pragma unroll
    for (int g = 0; g < 4; ++g)
        #pragma unroll
        for (int i = 0; i < 4; ++i) acc[g][i] = (floatx4){0.f, 0.f, 0.f, 0.f};

    #pragma unroll
    for (int chunk = 0; chunk < NH; ++chunk) {
        __syncthreads();                     // prev act readers done
        stage_h((chunk < 2) ? srcA : srcB, chunk & 1, act, tid, b, rb);
        __syncthreads();                     // writes visible
        const _Float16* wbase = wr + (size_t)(chunk * 9) * 8192 + (hg * 16 + n) * 32 + q * 8;
        #pragma unroll
        for (int tap = 0; tap < 9; ++tap) {
            half8 wfr[4];
            #pragma unroll
            for (int g = 0; g < 4; ++g)
                wfr[g] = *(const half8*)(wbase + (size_t)tap * 8192 + g * 2048);
            const int dy = tap / 3, dx = tap - dy * 3;
            half8 bfr[4];
            #pragma unroll
            for (int ni = 0; ni < 4; ++ni) {
                int row = rowsel + dy;                   // 0..3
                int col = 16 * ni + n + dx;              // 0..65
                bfr[ni] = *(const half8*)&act[((row * 66 + col) * 5 + q) * 8];
            }
            #pragma unroll
            for (int g = 0; g < 4; ++g)
                #pragma unroll
                for (int ni = 0; ni < 4; ++ni)
                    acc[g][ni] = __builtin_amdgcn_mfma_f32_16x16x32_f16(
                        wfr[g], bfr[ni], acc[g][ni], 0, 0, 0);
        }
    }

    if (XS) {
        // x-slab: B[k=tap][px] = x(row(px)-1+k/3, col(px)-1+k%3); px = rowsel*64+col
        __syncthreads();
        {
            // 128 px x 4 slots = 512 units, one per thread
            int pix = tid >> 2, sl = tid & 3;            // pix: row=pix>>6, cs=pix&63
            int row = pix >> 6, cs = pix & 63;
            half8 hv;
            #pragma unroll
            for (int j = 0; j < 8; ++j) hv[j] = (_Float16)0.f;
            const float* xb = xsrc + (size_t)b * (TSTEPS * HWSZ);
            int y0 = rb * 2 + row;
            if (sl == 0) {
                #pragma unroll
                for (int j = 0; j < 8; ++j) {
                    int gy = y0 - 1 + j / 3, gx = cs - 1 + j % 3;
                    if (gy >= 0 && gy < IMH && gx >= 0 && gx < IMW)
                        hv[j] = (_Float16)xb[gy * IMW + gx];
                }
            } else if (sl == 1) {
                int gy = y0 + 1, gx = cs + 1;            // tap 8: dy=2,dx=2
                if (gy < IMH && gx < IMW)
                    hv[0] = (_Float16)xb[gy * IMW + gx];
            }
            *(half8*)&act[(pix * 5 + sl) * 8] = hv;
        }
        __syncthreads();
        const _Float16* wbase = wr + (size_t)(NH * 9) * 8192 + (hg * 16 + n) * 32 + q * 8;
        half8 wfr[4];
        #pragma unroll
        for (int g = 0; g < 4; ++g)
            wfr[g] = *(const half8*)(wbase + g * 2048);
        half8 bfr[4];
        #pragma unroll
        for (int ni = 0; ni < 4; ++ni) {
            int pix = rowsel * 64 + 16 * ni + n;
            bfr[ni] = *(const half8*)&act[(pix * 5 + q) * 8];
        }
        #pragma unroll
        for (int g = 0; g < 4; ++g)
            #pragma unroll
            for (int ni = 0; ni < 4; ++ni)
                acc[g][ni] = __builtin_amdgcn_mfma_f32_16x16x32_f16(
                    wfr[g], bfr[ni], acc[g][ni], 0, 0, 0);
    }

    // Epilogue: lane holds gates for h = hg*16+q*4+r, pixel row rb*2+rowsel, col 16*ni+n
    const int hb = hg * 16 + q * 4;
    const int y = rb * 2 + rowsel;
    floatx4 bi = *(const floatx4*)&bias[hb];
    floatx4 bf = *(const floatx4*)&bias[64 + hb];
    floatx4 bo = *(const floatx4*)&bias[128 + hb];
    floatx4 bg = *(const floatx4*)&bias[192 + hb];
    #pragma unroll
    for (int ni = 0; ni < 4; ++ni) {
        int col = 16 * ni + n;
        size_t cidx = ((size_t)b * HWSZ + y * IMW + col) * 64 + hb;
        floatx4 cold = *(const floatx4*)&cpix[cidx];
        floatx4 cnew;
        half4 hv;
        #pragma unroll
        for (int r = 0; r < 4; ++r) {
            float zi = acc[0][ni][r] + bi[r];
            float zf = acc[1][ni][r] + bf[r];
            float zo = acc[2][ni][r] + bo[r];
            float zg = acc[3][ni][r] + bg[r];
            float cn = fmaf(sigmoidf_(zf), cold[r], sigmoidf_(zi) * tanhf_(zg));
            cnew[r] = cn;
            hv[r] = (_Float16)(sigmoidf_(zo) * tanhf_(cn));
        }
        *(floatx4*)&cpix[cidx] = cnew;
        *(half4*)&hpad[((size_t)(b * PADW + y + 1) * PADW + col + 1) * 64 + hb] = hv;
    }
}

// Merged dispatch: role 0 = layer1(t-1), role 1 = layer0(t). Roles independent.
__global__ __launch_bounds__(512, 4) void fused_step(
    const _Float16* __restrict__ a1, const _Float16* __restrict__ b1,
    _Float16* __restrict__ h1o, float* __restrict__ c1p,
    const _Float16* __restrict__ w1r, const float* __restrict__ bias1,
    const _Float16* __restrict__ a0, const float* __restrict__ x0,
    _Float16* __restrict__ h0o, float* __restrict__ c0p,
    const _Float16* __restrict__ w0r, const float* __restrict__ bias0,
    int role_single)
{
    __shared__ __align__(16) _Float16 act[264 * 5 * 8];   // 21.1 KB
    const int tid = threadIdx.x;
    const int rb = blockIdx.x, b = blockIdx.y;
    const int role = (gridDim.z == 2) ? (int)blockIdx.z : role_single;
    if (role == 0)
        lstm_body<4, false>(a1, b1, nullptr, h1o, c1p, w1r, bias1, act, tid, rb, b);
    else
        lstm_body<2, true>(a0, nullptr, x0, h0o, c0p, w0r, bias0, act, tid, rb, b);
}

__global__ void head_kernel(const _Float16* __restrict__ h1pad,
                            const float* __restrict__ wh,
                            const float* __restrict__ bh,
                            float* __restrict__ out) {
    int nn = blockIdx.x * blockDim.x + threadIdx.x;  // 0..65535
    int b = nn >> 12, pp = nn & 4095;
    int y = pp >> 6, xc = pp & 63;
    const _Float16* base = h1pad + ((size_t)(b * PADW + y + 1) * PADW + xc + 1) * 64;
    float s = bh[0];
    #pragma unroll
    for (int h0 = 0; h0 < 64; h0 += 8) {
        half8 hv = *(const half8*)&base[h0];
        #pragma unroll
        for (int j = 0; j < 8; ++j) s = fmaf((float)hv[j], wh[h0 + j], s);
    }
    out[nn] = fmaxf(s, 0.f);
}

extern "C" void kernel_launch(void* const* d_in, const int* in_sizes, int n_in,
                              void* d_out, int out_size, void* d_ws, size_t ws_size,
                              hipStream_t stream) {
    const float* x  = (const float*)d_in[0];
    const float* w0 = (const float*)d_in[1];
    const float* b0 = (const float*)d_in[2];
    const float* w1 = (const float*)d_in[3];
    const float* b1 = (const float*)d_in[4];
    const float* wh = (const float*)d_in[5];
    const float* bh = (const float*)d_in[6];
    float* out = (float*)d_out;

    const size_t HPAD = (size_t)BATCH * PADW * PADW * 64;  // 4,460,544 halves
    const size_t CBUF = (size_t)BATCH * HWSZ * 64;         // 4,194,304 floats
    _Float16* hp  = (_Float16*)d_ws;
    _Float16* h0a = hp;
    _Float16* h0b = hp + HPAD;
    _Float16* h1a = hp + 2 * HPAD;
    _Float16* h1b = hp + 3 * HPAD;
    float* cbase = (float*)(hp + 4 * HPAD);
    float* c0 = cbase;
    float* c1 = cbase + CBUF;
    _Float16* wr0 = (_Float16*)(cbase + 2 * CBUF);   // 19*8192 halves
    _Float16* wr1 = wr0 + (size_t)19 * 8192;         // 36*8192 halves

    // zero h buffers (borders must stay 0) and c buffers — ws is re-poisoned each call
    hipMemsetAsync(d_ws, 0, 4 * HPAD * sizeof(_Float16) + 2 * CBUF * sizeof(float), stream);
    repack_w0<<<608, 256, 0, stream>>>(w0, wr0);
    repack_w1<<<1152, 256, 0, stream>>>(w1, wr1);

    _Float16* h0buf[2] = {h0a, h0b};
    _Float16* h1buf[2] = {h1a, h1b};
    dim3 block(512);

    // D0: layer0(t=0) only: reads h0buf[0] (zeros) + x(0) -> writes h0buf[1], c0
    fused_step<<<dim3(32, BATCH, 1), block, 0, stream>>>(
        nullptr, nullptr, nullptr, nullptr, nullptr, nullptr,
        h0buf[0], x, h0buf[1], c0, wr0, b0, 1);

    // steady: z=0 -> L1(t-1), z=1 -> L0(t); both read h0_out(t-1) = h0buf[t&1]
    for (int t = 1; t < TSTEPS; ++t) {
        fused_step<<<dim3(32, BATCH, 2), block, 0, stream>>>(
            h0buf[t & 1], h1buf[(t - 1) & 1], h1buf[t & 1], c1, wr1, b1,
            h0buf[t & 1], x + (size_t)t * HWSZ, h0buf[(t + 1) & 1], c0, wr0, b0, 0);
    }

    // final: layer1(t=15): reads h0buf[0], h1buf[1] -> writes h1buf[0]
    fused_step<<<dim3(32, BATCH, 1), block, 0, stream>>>(
        h0buf[0], h1buf[1], h1buf[0], c1, wr1, b1,
        nullptr, nullptr, nullptr, nullptr, nullptr, nullptr, 0);

    head_kernel<<<256, 256, 0, stream>>>(h1buf[0], wh, bh, out);
}

// Round 13
// 1525.362 us; speedup vs baseline: 5.4284x; 5.4284x over previous
//
#include <hip/hip_runtime.h>

#define IMH 64
#define IMW 64
#define HWSZ 4096
#define BATCH 16
#define TSTEPS 16
#define PADW 66

typedef _Float16 half8 __attribute__((ext_vector_type(8)));
typedef _Float16 half4 __attribute__((ext_vector_type(4)));
typedef float floatx4 __attribute__((ext_vector_type(4)));
typedef int intx4 __attribute__((ext_vector_type(4)));

__device__ __forceinline__ float sigmoidf_(float x) { return 1.f / (1.f + __expf(-x)); }
__device__ __forceinline__ float tanhf_(float x) { return 1.f - 2.f / (1.f + __expf(2.f * x)); }

// layer1 weights: 36 slabs wr[gt][m][k32]; m=(g*4+hg)*16+i -> out=g*64+hg*16+i; ci=chunk*32+k.
__global__ void repack_w1(const float* __restrict__ w, _Float16* __restrict__ wr) {
    int total = 36 * 8192;
    for (int idx = blockIdx.x * blockDim.x + threadIdx.x; idx < total;
         idx += gridDim.x * blockDim.x) {
        int k = idx & 31;
        int m = (idx >> 5) & 255;
        int gt = idx >> 13;
        int chunk = gt / 9, tap = gt - chunk * 9;
        int g = m >> 6, hg = (m >> 4) & 3, i = m & 15;
        int out = g * 64 + hg * 16 + i;
        int ci = chunk * 32 + k;
        wr[idx] = (_Float16)w[(out * 128 + ci) * 9 + tap];
    }
}

// layer0 weights: 18 h-slabs (ci = chunk*32+k+1) + 1 x-slab (K-dim = tap: A[m][k]=w_x[out][k], k<9).
__global__ void repack_w0(const float* __restrict__ w, _Float16* __restrict__ wr) {
    int total = 19 * 8192;
    for (int idx = blockIdx.x * blockDim.x + threadIdx.x; idx < total;
         idx += gridDim.x * blockDim.x) {
        int k = idx & 31;
        int m = (idx >> 5) & 255;
        int gt = idx >> 13;
        int g = m >> 6, hg = (m >> 4) & 3, i = m & 15;
        int out = g * 64 + hg * 16 + i;
        float v = 0.f;
        if (gt < 18) {
            int chunk = gt / 9, tap = gt - chunk * 9;
            v = w[(out * 65 + (chunk * 32 + k + 1)) * 9 + tap];
        } else if (k < 9) {
            v = w[(out * 65 + 0) * 9 + k];   // x-plane, tap k
        }
        wr[idx] = (_Float16)v;
    }
}

// ---- R11 champion block structure: 256 thr = 4 waves = 4 hid-groups,
// ---- ONE image row x 64 cols, wave tile M=64 x N=64, VGPR 64 + AGPR 64 (locked).

// stage 3 halo rows x 66 cols x 32 ch -> 792 16B units; 5-slot (80B) pixel stride.
// 32-bit offsets only (buffers < 2 GB) to minimize address-register pressure.
__device__ __forceinline__ void stage_h(const _Float16* __restrict__ buf, int halfsel,
                                        _Float16* __restrict__ act, int tid, int b, int rb) {
    const int rowbase = (b * PADW + rb) * PADW;        // padded row origin (pixels)
    for (int t = tid; t < 792; t += 256) {
        int pix = t >> 2, sl = t & 3;
        int r = pix / 66, cs = pix - r * 66;
        int gofs = ((rowbase + r * PADW + cs) << 6) + (halfsel << 5) + (sl << 3);
        *(intx4*)&act[(pix * 5 + sl) * 8] = *(const intx4*)(buf + gofs);
    }
}

// NH = number of 32-ch h chunks; XS = append single x-slab (taps in K-dim)
template<int NH, bool XS>
__device__ __forceinline__ void lstm_body(
    const _Float16* __restrict__ srcA,    // h chunks 0-1
    const _Float16* __restrict__ srcB,    // h chunks 2-3
    const float* __restrict__ xsrc,       // layer0 x_t
    _Float16* __restrict__ hpad,          // out h [B][66][66][64]
    float* __restrict__ cpix,             // in-place c [B][4096][64]
    const _Float16* __restrict__ wr,      // [NH*9(+1)][256][32]
    const float* __restrict__ bias,       // [256]
    _Float16* __restrict__ act,           // LDS, 198*5*8 halves
    int tid, int rb, int b)
{
    const int lane = tid & 63;
    const int n = lane & 15, q = lane >> 4;
    const int hg = tid >> 6;

    floatx4 acc[4][4];
    #pragma unroll
    for (int g = 0; g < 4; ++g)
        #pragma unroll
        for (int i = 0; i < 4; ++i) acc[g][i] = (floatx4){0.f, 0.f, 0.f, 0.f};

    #pragma unroll
    for (int chunk = 0; chunk < NH; ++chunk) {
        __syncthreads();                     // prev act readers done
        stage_h((chunk < 2) ? srcA : srcB, chunk & 1, act, tid, b, rb);
        __syncthreads();                     // writes visible
        const _Float16* wbase = wr + (chunk * 9) * 8192 + (hg * 16 + n) * 32 + q * 8;
        #pragma unroll
        for (int tap = 0; tap < 9; ++tap) {
            half8 wfr[4];
            #pragma unroll
            for (int g = 0; g < 4; ++g)
                wfr[g] = *(const half8*)(wbase + tap * 8192 + g * 2048);
            const int dy = tap / 3, dx = tap - dy * 3;
            half8 bfr[4];
            #pragma unroll
            for (int ni = 0; ni < 4; ++ni) {
                int col = 16 * ni + n + dx;
                bfr[ni] = *(const half8*)&act[((dy * 66 + col) * 5 + q) * 8];
            }
            #pragma unroll
            for (int g = 0; g < 4; ++g)
                #pragma unroll
                for (int ni = 0; ni < 4; ++ni)
                    acc[g][ni] = __builtin_amdgcn_mfma_f32_16x16x32_f16(
                        wfr[g], bfr[ni], acc[g][ni], 0, 0, 0);
        }
    }

    if (XS) {
        // x-slab: B[k=tap][col] = x(rb-1+k/3, col-1+k%3), single K=32 slab (k>=9 zero)
        __syncthreads();
        {
            int pix = tid >> 2, sl = tid & 3;
            half8 hv;
            #pragma unroll
            for (int j = 0; j < 8; ++j) hv[j] = (_Float16)0.f;
            const float* xb = xsrc + b * (TSTEPS * HWSZ);
            if (sl == 0) {
                #pragma unroll
                for (int j = 0; j < 8; ++j) {
                    int gy = rb - 1 + j / 3, gx = pix - 1 + j % 3;
                    if (gy >= 0 && gy < IMH && gx >= 0 && gx < IMW)
                        hv[j] = (_Float16)xb[gy * IMW + gx];
                }
            } else if (sl == 1) {
                int gy = rb + 1, gx = pix + 1;           // tap 8: dy=2,dx=2
                if (gy < IMH && gx < IMW)
                    hv[0] = (_Float16)xb[gy * IMW + gx];
            }
            *(half8*)&act[(pix * 5 + sl) * 8] = hv;
        }
        __syncthreads();
        const _Float16* wbase = wr + (NH * 9) * 8192 + (hg * 16 + n) * 32 + q * 8;
        half8 wfr[4];
        #pragma unroll
        for (int g = 0; g < 4; ++g)
            wfr[g] = *(const half8*)(wbase + g * 2048);
        half8 bfr[4];
        #pragma unroll
        for (int ni = 0; ni < 4; ++ni)
            bfr[ni] = *(const half8*)&act[((16 * ni + n) * 5 + q) * 8];
        #pragma unroll
        for (int g = 0; g < 4; ++g)
            #pragma unroll
            for (int ni = 0; ni < 4; ++ni)
                acc[g][ni] = __builtin_amdgcn_mfma_f32_16x16x32_f16(
                    wfr[g], bfr[ni], acc[g][ni], 0, 0, 0);
    }

    // Epilogue: lane holds gates for h = hg*16+q*4+r, pixel row rb, col 16*ni+n
    const int hb = hg * 16 + q * 4;
    floatx4 bi = *(const floatx4*)&bias[hb];
    floatx4 bf = *(const floatx4*)&bias[64 + hb];
    floatx4 bo = *(const floatx4*)&bias[128 + hb];
    floatx4 bg = *(const floatx4*)&bias[192 + hb];
    #pragma unroll
    for (int ni = 0; ni < 4; ++ni) {
        int col = 16 * ni + n;
        int cidx = ((b * HWSZ + rb * IMW + col) << 6) + hb;      // 32-bit offset
        floatx4 cold = *(const floatx4*)(cpix + cidx);
        floatx4 cnew;
        half4 hv;
        #pragma unroll
        for (int r = 0; r < 4; ++r) {
            float zi = acc[0][ni][r] + bi[r];
            float zf = acc[1][ni][r] + bf[r];
            float zo = acc[2][ni][r] + bo[r];
            float zg = acc[3][ni][r] + bg[r];
            float cn = fmaf(sigmoidf_(zf), cold[r], sigmoidf_(zi) * tanhf_(zg));
            cnew[r] = cn;
            hv[r] = (_Float16)(sigmoidf_(zo) * tanhf_(cn));
        }
        *(floatx4*)(cpix + cidx) = cnew;
        int hidx = (((b * PADW + rb + 1) * PADW + col + 1) << 6) + hb;
        *(half4*)(hpad + hidx) = hv;
    }
}

// Merged dispatch: role 0 = layer1(t-1), role 1 = layer0(t). Roles independent
// (both only READ h0_out(t-1); writes go to disjoint buffers). grid.z=2 runs both.
__global__ __launch_bounds__(256, 4) void fused_step(
    const _Float16* __restrict__ a1, const _Float16* __restrict__ b1,
    _Float16* __restrict__ h1o, float* __restrict__ c1p,
    const _Float16* __restrict__ w1r, const float* __restrict__ bias1,
    const _Float16* __restrict__ a0, const float* __restrict__ x0,
    _Float16* __restrict__ h0o, float* __restrict__ c0p,
    const _Float16* __restrict__ w0r, const float* __restrict__ bias0,
    int role_single)
{
    __shared__ __align__(16) _Float16 act[198 * 5 * 8];   // 15.8 KB
    const int tid = threadIdx.x;
    const int rb = blockIdx.x, b = blockIdx.y;
    const int role = (gridDim.z == 2) ? (int)blockIdx.z : role_single;
    if (role == 0)
        lstm_body<4, false>(a1, b1, nullptr, h1o, c1p, w1r, bias1, act, tid, rb, b);
    else
        lstm_body<2, true>(a0, nullptr, x0, h0o, c0p, w0r, bias0, act, tid, rb, b);
}

__global__ void head_kernel(const _Float16* __restrict__ h1pad,
                            const float* __restrict__ wh,
                            const float* __restrict__ bh,
                            float* __restrict__ out) {
    int nn = blockIdx.x * blockDim.x + threadIdx.x;  // 0..65535
    int b = nn >> 12, pp = nn & 4095;
    int y = pp >> 6, xc = pp & 63;
    const _Float16* base = h1pad + (((b * PADW + y + 1) * PADW + xc + 1) << 6);
    float s = bh[0];
    #pragma unroll
    for (int h0 = 0; h0 < 64; h0 += 8) {
        half8 hv = *(const half8*)&base[h0];
        #pragma unroll
        for (int j = 0; j < 8; ++j) s = fmaf((float)hv[j], wh[h0 + j], s);
    }
    out[nn] = fmaxf(s, 0.f);
}

extern "C" void kernel_launch(void* const* d_in, const int* in_sizes, int n_in,
                              void* d_out, int out_size, void* d_ws, size_t ws_size,
                              hipStream_t stream) {
    const float* x  = (const float*)d_in[0];
    const float* w0 = (const float*)d_in[1];
    const float* b0 = (const float*)d_in[2];
    const float* w1 = (const float*)d_in[3];
    const float* b1 = (const float*)d_in[4];
    const float* wh = (const float*)d_in[5];
    const float* bh = (const float*)d_in[6];
    float* out = (float*)d_out;

    const size_t HPAD = (size_t)BATCH * PADW * PADW * 64;  // 4,460,544 halves
    const size_t CBUF = (size_t)BATCH * HWSZ * 64;         // 4,194,304 floats
    _Float16* hp  = (_Float16*)d_ws;
    _Float16* h0a = hp;
    _Float16* h0b = hp + HPAD;
    _Float16* h1a = hp + 2 * HPAD;
    _Float16* h1b = hp + 3 * HPAD;
    float* cbase = (float*)(hp + 4 * HPAD);
    float* c0 = cbase;
    float* c1 = cbase + CBUF;
    _Float16* wr0 = (_Float16*)(cbase + 2 * CBUF);   // 19*8192 halves
    _Float16* wr1 = wr0 + (size_t)19 * 8192;         // 36*8192 halves

    // zero h buffers (borders must stay 0) and c buffers — ws is re-poisoned each call
    hipMemsetAsync(d_ws, 0, 4 * HPAD * sizeof(_Float16) + 2 * CBUF * sizeof(float), stream);
    repack_w0<<<608, 256, 0, stream>>>(w0, wr0);
    repack_w1<<<1152, 256, 0, stream>>>(w1, wr1);

    _Float16* h0buf[2] = {h0a, h0b};
    _Float16* h1buf[2] = {h1a, h1b};
    dim3 block(256);

    // D0: layer0(t=0) only: reads h0buf[0] (zeros) + x(0) -> writes h0buf[1], c0
    fused_step<<<dim3(64, BATCH, 1), block, 0, stream>>>(
        nullptr, nullptr, nullptr, nullptr, nullptr, nullptr,
        h0buf[0], x, h0buf[1], c0, wr0, b0, 1);

    // steady: z=0 -> L1(t-1), z=1 -> L0(t); both read h0_out(t-1) = h0buf[t&1]
    for (int t = 1; t < TSTEPS; ++t) {
        fused_step<<<dim3(64, BATCH, 2), block, 0, stream>>>(
            h0buf[t & 1], h1buf[(t - 1) & 1], h1buf[t & 1], c1, wr1, b1,
            h0buf[t & 1], x + (size_t)t * HWSZ, h0buf[(t + 1) & 1], c0, wr0, b0, 0);
    }

    // final: layer1(t=15): reads h0buf[0], h1buf[1] -> writes h1buf[0]
    fused_step<<<dim3(64, BATCH, 1), block, 0, stream>>>(
        h0buf[0], h1buf[1], h1buf[0], c1, wr1, b1,
        nullptr, nullptr, nullptr, nullptr, nullptr, nullptr, 0);

    head_kernel<<<256, 256, 0, stream>>>(h1buf[0], wh, bh, out);
}

// Round 14
// 1507.584 us; speedup vs baseline: 5.4924x; 1.0118x over previous
//
#include <hip/hip_runtime.h>

#define IMH 64
#define IMW 64
#define HWSZ 4096
#define BATCH 16
#define TSTEPS 16
#define PADW 66

typedef _Float16 half8 __attribute__((ext_vector_type(8)));
typedef _Float16 half4 __attribute__((ext_vector_type(4)));
typedef float floatx4 __attribute__((ext_vector_type(4)));
typedef int intx4 __attribute__((ext_vector_type(4)));

__device__ __forceinline__ float sigmoidf_(float x) { return 1.f / (1.f + __expf(-x)); }
__device__ __forceinline__ float tanhf_(float x) { return 1.f - 2.f / (1.f + __expf(2.f * x)); }

// layer1 weights: 36 slabs wr[gt][m][k32]; m=(g*4+hg)*16+i -> out=g*64+hg*16+i; ci=chunk*32+k.
__global__ void repack_w1(const float* __restrict__ w, _Float16* __restrict__ wr) {
    int total = 36 * 8192;
    for (int idx = blockIdx.x * blockDim.x + threadIdx.x; idx < total;
         idx += gridDim.x * blockDim.x) {
        int k = idx & 31;
        int m = (idx >> 5) & 255;
        int gt = idx >> 13;
        int chunk = gt / 9, tap = gt - chunk * 9;
        int g = m >> 6, hg = (m >> 4) & 3, i = m & 15;
        int out = g * 64 + hg * 16 + i;
        int ci = chunk * 32 + k;
        wr[idx] = (_Float16)w[(out * 128 + ci) * 9 + tap];
    }
}

// layer0 weights: 18 h-slabs (ci = chunk*32+k+1) + 1 x-slab (K-dim = tap: A[m][k]=w_x[out][k], k<9).
__global__ void repack_w0(const float* __restrict__ w, _Float16* __restrict__ wr) {
    int total = 19 * 8192;
    for (int idx = blockIdx.x * blockDim.x + threadIdx.x; idx < total;
         idx += gridDim.x * blockDim.x) {
        int k = idx & 31;
        int m = (idx >> 5) & 255;
        int gt = idx >> 13;
        int g = m >> 6, hg = (m >> 4) & 3, i = m & 15;
        int out = g * 64 + hg * 16 + i;
        float v = 0.f;
        if (gt < 18) {
            int chunk = gt / 9, tap = gt - chunk * 9;
            v = w[(out * 65 + (chunk * 32 + k + 1)) * 9 + tap];
        } else if (k < 9) {
            v = w[(out * 65 + 0) * 9 + k];   // x-plane, tap k
        }
        wr[idx] = (_Float16)v;
    }
}

// zero ONLY the halo border ring of the 4 contiguous h buffers (interiors are
// always written before read now that zero-h contributions are skipped).
__global__ void border_zero(_Float16* hp) {
    const int total = 4 * BATCH * 260 * 16;          // units of half4
    int idx = blockIdx.x * blockDim.x + threadIdx.x;
    if (idx >= total) return;
    int u = idx & 15;
    int t = idx >> 4;
    int e = t % 260; t /= 260;
    int b = t & 15;
    int buf = t >> 4;
    int py, px;
    if (e < 66)       { py = 0;       px = e; }
    else if (e < 132) { py = 65;      px = e - 66; }
    else if (e < 196) { py = e - 131; px = 0; }
    else              { py = e - 195; px = 65; }
    _Float16* p = hp + (size_t)buf * (BATCH * PADW * PADW * 64)
                + (((b * PADW + py) * PADW + px) << 6) + u * 4;
    *(half4*)p = (half4){(_Float16)0.f, (_Float16)0.f, (_Float16)0.f, (_Float16)0.f};
}

// ---- champion block structure (R13): 256 thr = 4 waves = 4 hid-groups,
// ---- ONE image row x 64 cols, wave tile M=64 x N=64, VGPR 64 + AGPR 64 (locked).

__device__ __forceinline__ void stage_h(const _Float16* __restrict__ buf, int halfsel,
                                        _Float16* __restrict__ act, int tid, int b, int rb) {
    const int rowbase = (b * PADW + rb) * PADW;
    for (int t = tid; t < 792; t += 256) {
        int pix = t >> 2, sl = t & 3;
        int r = pix / 66, cs = pix - r * 66;
        int gofs = ((rowbase + r * PADW + cs) << 6) + (halfsel << 5) + (sl << 3);
        *(intx4*)&act[(pix * 5 + sl) * 8] = *(const intx4*)(buf + gofs);
    }
}

// NH = number of 32-ch h chunks (0 skips all h work); XS = append single x-slab;
// CLOAD = load previous c (false: c_prev == 0 exactly, skip the load).
template<int NH, bool XS, bool CLOAD>
__device__ __forceinline__ void lstm_body(
    const _Float16* __restrict__ srcA,    // h chunks 0-1
    const _Float16* __restrict__ srcB,    // h chunks 2-3
    const float* __restrict__ xsrc,       // layer0 x_t
    _Float16* __restrict__ hpad,          // out h [B][66][66][64]
    float* __restrict__ cpix,             // in-place c [B][4096][64]
    const _Float16* __restrict__ wr,      // [NH*9(+1)][256][32]
    const float* __restrict__ bias,       // [256]
    _Float16* __restrict__ act,           // LDS, 198*5*8 halves
    int tid, int rb, int b)
{
    const int lane = tid & 63;
    const int n = lane & 15, q = lane >> 4;
    const int hg = tid >> 6;

    floatx4 acc[4][4];
    #pragma unroll
    for (int g = 0; g < 4; ++g)
        #pragma unroll
        for (int i = 0; i < 4; ++i) acc[g][i] = (floatx4){0.f, 0.f, 0.f, 0.f};

    #pragma unroll
    for (int chunk = 0; chunk < NH; ++chunk) {
        __syncthreads();                     // prev act readers done
        stage_h((chunk < 2) ? srcA : srcB, chunk & 1, act, tid, b, rb);
        __syncthreads();                     // writes visible
        const _Float16* wbase = wr + (chunk * 9) * 8192 + (hg * 16 + n) * 32 + q * 8;
        #pragma unroll
        for (int tap = 0; tap < 9; ++tap) {
            half8 wfr[4];
            #pragma unroll
            for (int g = 0; g < 4; ++g)
                wfr[g] = *(const half8*)(wbase + tap * 8192 + g * 2048);
            const int dy = tap / 3, dx = tap - dy * 3;
            half8 bfr[4];
            #pragma unroll
            for (int ni = 0; ni < 4; ++ni) {
                int col = 16 * ni + n + dx;
                bfr[ni] = *(const half8*)&act[((dy * 66 + col) * 5 + q) * 8];
            }
            #pragma unroll
            for (int g = 0; g < 4; ++g)
                #pragma unroll
                for (int ni = 0; ni < 4; ++ni)
                    acc[g][ni] = __builtin_amdgcn_mfma_f32_16x16x32_f16(
                        wfr[g], bfr[ni], acc[g][ni], 0, 0, 0);
        }
    }

    if (XS) {
        // x-slab: B[k=tap][col] = x(rb-1+k/3, col-1+k%3), single K=32 slab (k>=9 zero)
        __syncthreads();
        {
            int pix = tid >> 2, sl = tid & 3;
            half8 hv;
            #pragma unroll
            for (int j = 0; j < 8; ++j) hv[j] = (_Float16)0.f;
            const float* xb = xsrc + b * (TSTEPS * HWSZ);
            if (sl == 0) {
                #pragma unroll
                for (int j = 0; j < 8; ++j) {
                    int gy = rb - 1 + j / 3, gx = pix - 1 + j % 3;
                    if (gy >= 0 && gy < IMH && gx >= 0 && gx < IMW)
                        hv[j] = (_Float16)xb[gy * IMW + gx];
                }
            } else if (sl == 1) {
                int gy = rb + 1, gx = pix + 1;           // tap 8: dy=2,dx=2
                if (gy < IMH && gx < IMW)
                    hv[0] = (_Float16)xb[gy * IMW + gx];
            }
            *(half8*)&act[(pix * 5 + sl) * 8] = hv;
        }
        __syncthreads();
        const _Float16* wbase = wr + (NH * 9) * 8192 + (hg * 16 + n) * 32 + q * 8;
        half8 wfr[4];
        #pragma unroll
        for (int g = 0; g < 4; ++g)
            wfr[g] = *(const half8*)(wbase + g * 2048);
        half8 bfr[4];
        #pragma unroll
        for (int ni = 0; ni < 4; ++ni)
            bfr[ni] = *(const half8*)&act[((16 * ni + n) * 5 + q) * 8];
        #pragma unroll
        for (int g = 0; g < 4; ++g)
            #pragma unroll
            for (int ni = 0; ni < 4; ++ni)
                acc[g][ni] = __builtin_amdgcn_mfma_f32_16x16x32_f16(
                    wfr[g], bfr[ni], acc[g][ni], 0, 0, 0);
    }

    // Epilogue: lane holds gates for h = hg*16+q*4+r, pixel row rb, col 16*ni+n
    const int hb = hg * 16 + q * 4;
    floatx4 bi = *(const floatx4*)&bias[hb];
    floatx4 bf = *(const floatx4*)&bias[64 + hb];
    floatx4 bo = *(const floatx4*)&bias[128 + hb];
    floatx4 bg = *(const floatx4*)&bias[192 + hb];
    #pragma unroll
    for (int ni = 0; ni < 4; ++ni) {
        int col = 16 * ni + n;
        int cidx = ((b * HWSZ + rb * IMW + col) << 6) + hb;      // 32-bit offset
        floatx4 cold;
        if (CLOAD) cold = *(const floatx4*)(cpix + cidx);
        else       cold = (floatx4){0.f, 0.f, 0.f, 0.f};
        floatx4 cnew;
        half4 hv;
        #pragma unroll
        for (int r = 0; r < 4; ++r) {
            float zi = acc[0][ni][r] + bi[r];
            float zf = acc[1][ni][r] + bf[r];
            float zo = acc[2][ni][r] + bo[r];
            float zg = acc[3][ni][r] + bg[r];
            float cn = CLOAD ? fmaf(sigmoidf_(zf), cold[r], sigmoidf_(zi) * tanhf_(zg))
                             : sigmoidf_(zi) * tanhf_(zg);
            cnew[r] = cn;
            hv[r] = (_Float16)(sigmoidf_(zo) * tanhf_(cn));
        }
        *(floatx4*)(cpix + cidx) = cnew;
        int hidx = (((b * PADW + rb + 1) * PADW + col + 1) << 6) + hb;
        *(half4*)(hpad + hidx) = hv;
    }
}

// ZMODE: 0 = role0 (L1) only, 1 = role1 (L0) only, 2 = both via blockIdx.z.
template<int NH1, bool C1, int NH0, bool XS0, bool C0, int ZMODE>
__global__ __launch_bounds__(256, 4) void fused_step(
    const _Float16* __restrict__ a1, const _Float16* __restrict__ b1,
    _Float16* __restrict__ h1o, float* __restrict__ c1p,
    const _Float16* __restrict__ w1r, const float* __restrict__ bias1,
    const _Float16* __restrict__ a0, const float* __restrict__ x0,
    _Float16* __restrict__ h0o, float* __restrict__ c0p,
    const _Float16* __restrict__ w0r, const float* __restrict__ bias0)
{
    __shared__ __align__(16) _Float16 act[198 * 5 * 8];   // 15.8 KB
    const int tid = threadIdx.x;
    const int rb = blockIdx.x, b = blockIdx.y;
    const int role = (ZMODE == 2) ? (int)blockIdx.z : ZMODE;
    if (ZMODE != 1 && role == 0)
        lstm_body<NH1, false, C1>(a1, b1, nullptr, h1o, c1p, w1r, bias1, act, tid, rb, b);
    else
        lstm_body<NH0, XS0, C0>(a0, nullptr, x0, h0o, c0p, w0r, bias0, act, tid, rb, b);
}

__global__ void head_kernel(const _Float16* __restrict__ h1pad,
                            const float* __restrict__ wh,
                            const float* __restrict__ bh,
                            float* __restrict__ out) {
    int nn = blockIdx.x * blockDim.x + threadIdx.x;  // 0..65535
    int b = nn >> 12, pp = nn & 4095;
    int y = pp >> 6, xc = pp & 63;
    const _Float16* base = h1pad + (((b * PADW + y + 1) * PADW + xc + 1) << 6);
    float s = bh[0];
    #pragma unroll
    for (int h0 = 0; h0 < 64; h0 += 8) {
        half8 hv = *(const half8*)&base[h0];
        #pragma unroll
        for (int j = 0; j < 8; ++j) s = fmaf((float)hv[j], wh[h0 + j], s);
    }
    out[nn] = fmaxf(s, 0.f);
}

extern "C" void kernel_launch(void* const* d_in, const int* in_sizes, int n_in,
                              void* d_out, int out_size, void* d_ws, size_t ws_size,
                              hipStream_t stream) {
    const float* x  = (const float*)d_in[0];
    const float* w0 = (const float*)d_in[1];
    const float* b0 = (const float*)d_in[2];
    const float* w1 = (const float*)d_in[3];
    const float* b1 = (const float*)d_in[4];
    const float* wh = (const float*)d_in[5];
    const float* bh = (const float*)d_in[6];
    float* out = (float*)d_out;

    const size_t HPAD = (size_t)BATCH * PADW * PADW * 64;  // 4,460,544 halves
    const size_t CBUF = (size_t)BATCH * HWSZ * 64;         // 4,194,304 floats
    _Float16* hp  = (_Float16*)d_ws;
    _Float16* h0a = hp;
    _Float16* h0b = hp + HPAD;
    _Float16* h1a = hp + 2 * HPAD;
    _Float16* h1b = hp + 3 * HPAD;
    float* cbase = (float*)(hp + 4 * HPAD);
    float* c0 = cbase;
    float* c1 = cbase + CBUF;
    _Float16* wr0 = (_Float16*)(cbase + 2 * CBUF);   // 19*8192 halves
    _Float16* wr1 = wr0 + (size_t)19 * 8192;         // 36*8192 halves

    // Only h BORDERS need zeroing (interiors & c are written before read).
    border_zero<<<1040, 256, 0, stream>>>(hp);
    repack_w0<<<608, 256, 0, stream>>>(w0, wr0);
    repack_w1<<<1152, 256, 0, stream>>>(w1, wr1);

    _Float16* h0buf[2] = {h0a, h0b};
    _Float16* h1buf[2] = {h1a, h1b};
    dim3 block(256);

    // D0 = L0(0): h0(-1)=0 -> x-slab only (NH=0), c0(-1)=0 -> no c load.
    // x-slab sits at slab index 0 of the passed pointer -> wr0 + 18 slabs.
    fused_step<0, false, 0, true, false, 1><<<dim3(64, BATCH, 1), block, 0, stream>>>(
        nullptr, nullptr, nullptr, nullptr, nullptr, nullptr,
        nullptr, x, h0buf[1], c0, wr0 + (size_t)18 * 8192, b0);

    // D1 (t=1): role0 = L1(0): h1(-1)=0 -> only h0new chunks (NH=2), no c1 load.
    //           role1 = L0(1): full (NH=2 + x-slab, c0 load).
    fused_step<2, false, 2, true, true, 2><<<dim3(64, BATCH, 2), block, 0, stream>>>(
        h0buf[1], nullptr, h1buf[1], c1, wr1, b1,
        h0buf[1], x + (size_t)HWSZ, h0buf[0], c0, wr0, b0);

    // steady t=2..15: role0 = L1(t-1) full; role1 = L0(t) full.
    for (int t = 2; t < TSTEPS; ++t) {
        fused_step<4, true, 2, true, true, 2><<<dim3(64, BATCH, 2), block, 0, stream>>>(
            h0buf[t & 1], h1buf[(t - 1) & 1], h1buf[t & 1], c1, wr1, b1,
            h0buf[t & 1], x + (size_t)t * HWSZ, h0buf[(t + 1) & 1], c0, wr0, b0);
    }

    // final: L1(15): reads h0new(15)=h0buf[0], h1(14)=h1buf[1] -> writes h1buf[0]
    fused_step<4, true, 0, false, false, 0><<<dim3(64, BATCH, 1), block, 0, stream>>>(
        h0buf[0], h1buf[1], h1buf[0], c1, wr1, b1,
        nullptr, nullptr, nullptr, nullptr, nullptr, nullptr);

    head_kernel<<<256, 256, 0, stream>>>(h1buf[0], wh, bh, out);
}

// Round 15
// 1495.697 us; speedup vs baseline: 5.5361x; 1.0079x over previous
//
#include <hip/hip_runtime.h>

#define IMH 64
#define IMW 64
#define HWSZ 4096
#define BATCH 16
#define TSTEPS 16
#define PADW 66

typedef _Float16 half8 __attribute__((ext_vector_type(8)));
typedef _Float16 half4 __attribute__((ext_vector_type(4)));
typedef float floatx4 __attribute__((ext_vector_type(4)));
typedef int intx4 __attribute__((ext_vector_type(4)));

__device__ __forceinline__ float sigmoidf_(float x) { return 1.f / (1.f + __expf(-x)); }
__device__ __forceinline__ float tanhf_(float x) { return 1.f - 2.f / (1.f + __expf(2.f * x)); }

// layer1 weights: 36 slabs wr[gt][m][k32]; m=(g*4+hg)*16+i -> out=g*64+hg*16+i; ci=chunk*32+k.
__global__ void repack_w1(const float* __restrict__ w, _Float16* __restrict__ wr) {
    int total = 36 * 8192;
    for (int idx = blockIdx.x * blockDim.x + threadIdx.x; idx < total;
         idx += gridDim.x * blockDim.x) {
        int k = idx & 31;
        int m = (idx >> 5) & 255;
        int gt = idx >> 13;
        int chunk = gt / 9, tap = gt - chunk * 9;
        int g = m >> 6, hg = (m >> 4) & 3, i = m & 15;
        int out = g * 64 + hg * 16 + i;
        int ci = chunk * 32 + k;
        wr[idx] = (_Float16)w[(out * 128 + ci) * 9 + tap];
    }
}

// layer0 weights: 18 h-slabs (ci = chunk*32+k+1) + 1 x-slab (K-dim = tap: A[m][k]=w_x[out][k], k<9).
__global__ void repack_w0(const float* __restrict__ w, _Float16* __restrict__ wr) {
    int total = 19 * 8192;
    for (int idx = blockIdx.x * blockDim.x + threadIdx.x; idx < total;
         idx += gridDim.x * blockDim.x) {
        int k = idx & 31;
        int m = (idx >> 5) & 255;
        int gt = idx >> 13;
        int g = m >> 6, hg = (m >> 4) & 3, i = m & 15;
        int out = g * 64 + hg * 16 + i;
        float v = 0.f;
        if (gt < 18) {
            int chunk = gt / 9, tap = gt - chunk * 9;
            v = w[(out * 65 + (chunk * 32 + k + 1)) * 9 + tap];
        } else if (k < 9) {
            v = w[(out * 65 + 0) * 9 + k];   // x-plane, tap k
        }
        wr[idx] = (_Float16)v;
    }
}

// zero ONLY the halo border ring of the 4 contiguous h buffers.
__global__ void border_zero(_Float16* hp) {
    const int total = 4 * BATCH * 260 * 16;          // units of half4
    int idx = blockIdx.x * blockDim.x + threadIdx.x;
    if (idx >= total) return;
    int u = idx & 15;
    int t = idx >> 4;
    int e = t % 260; t /= 260;
    int b = t & 15;
    int buf = t >> 4;
    int py, px;
    if (e < 66)       { py = 0;       px = e; }
    else if (e < 132) { py = 65;      px = e - 66; }
    else if (e < 196) { py = e - 131; px = 0; }
    else              { py = e - 195; px = 65; }
    _Float16* p = hp + (size_t)buf * (BATCH * PADW * PADW * 64)
                + (((b * PADW + py) * PADW + px) << 6) + u * 4;
    *(half4*)p = (half4){(_Float16)0.f, (_Float16)0.f, (_Float16)0.f, (_Float16)0.f};
}

// ---- champion block structure: 256 thr = 4 waves = 4 hid-groups,
// ---- ONE image row x 64 cols, wave tile M=64 x N=64, VGPR 64 + AGPR 64 (locked).

__device__ __forceinline__ void stage_h(const _Float16* __restrict__ buf, int halfsel,
                                        _Float16* __restrict__ act, int tid, int b, int rb) {
    const int rowbase = (b * PADW + rb) * PADW;
    for (int t = tid; t < 792; t += 256) {
        int pix = t >> 2, sl = t & 3;
        int r = pix / 66, cs = pix - r * 66;
        int gofs = ((rowbase + r * PADW + cs) << 6) + (halfsel << 5) + (sl << 3);
        *(intx4*)&act[(pix * 5 + sl) * 8] = *(const intx4*)(buf + gofs);
    }
}

// NH = # of 32-ch h chunks; XS = append x-slab (taps in K-dim, staged in xact at
// kernel start — chunk-loop barriers order it); CLOAD = load previous c;
// HEAD = fuse 1x1-conv+ReLU head, skip h/c stores (final dispatch only).
template<int NH, bool XS, bool CLOAD, bool HEAD>
__device__ __forceinline__ void lstm_body(
    const _Float16* __restrict__ srcA,    // h chunks 0-1
    const _Float16* __restrict__ srcB,    // h chunks 2-3
    const float* __restrict__ xsrc,       // layer0 x_t
    _Float16* __restrict__ hpad,          // out h [B][66][66][64]
    float* __restrict__ cpix,             // in-place c [B][4096][64]
    const _Float16* __restrict__ wr,      // [NH*9(+1)][256][32]
    const float* __restrict__ bias,       // [256]
    const float* __restrict__ wh,         // [64]  (HEAD)
    const float* __restrict__ bh,         // [1]   (HEAD)
    float* __restrict__ outp,             // [B][64][64] (HEAD)
    _Float16* __restrict__ act,           // LDS, 198*5*8 halves
    _Float16* __restrict__ extra,         // LDS, 5120 halves: x-slab (XS) / head scratch
    int tid, int rb, int b)
{
    const int lane = tid & 63;
    const int n = lane & 15, q = lane >> 4;
    const int hg = tid >> 6;

    if (XS) {
        // x-slab staging at block start: B[k=tap][col], col=pix, k=sl*8+j (k>=9 zero)
        int pix = tid >> 2, sl = tid & 3;
        half8 hv;
        #pragma unroll
        for (int j = 0; j < 8; ++j) hv[j] = (_Float16)0.f;
        const float* xb = xsrc + b * (TSTEPS * HWSZ);
        if (sl == 0) {
            #pragma unroll
            for (int j = 0; j < 8; ++j) {
                int gy = rb - 1 + j / 3, gx = pix - 1 + j % 3;
                if (gy >= 0 && gy < IMH && gx >= 0 && gx < IMW)
                    hv[j] = (_Float16)xb[gy * IMW + gx];
            }
        } else if (sl == 1) {
            int gy = rb + 1, gx = pix + 1;               // tap 8: dy=2,dx=2
            if (gy < IMH && gx < IMW)
                hv[0] = (_Float16)xb[gy * IMW + gx];
        }
        *(half8*)&extra[(pix * 5 + sl) * 8] = hv;
    }

    floatx4 acc[4][4];
    #pragma unroll
    for (int g = 0; g < 4; ++g)
        #pragma unroll
        for (int i = 0; i < 4; ++i) acc[g][i] = (floatx4){0.f, 0.f, 0.f, 0.f};

    #pragma unroll
    for (int chunk = 0; chunk < NH; ++chunk) {
        __syncthreads();                     // prev act readers done (orders xact too)
        stage_h((chunk < 2) ? srcA : srcB, chunk & 1, act, tid, b, rb);
        __syncthreads();                     // writes visible
        const _Float16* wbase = wr + (chunk * 9) * 8192 + (hg * 16 + n) * 32 + q * 8;
        #pragma unroll
        for (int tap = 0; tap < 9; ++tap) {
            half8 wfr[4];
            #pragma unroll
            for (int g = 0; g < 4; ++g)
                wfr[g] = *(const half8*)(wbase + tap * 8192 + g * 2048);
            const int dy = tap / 3, dx = tap - dy * 3;
            half8 bfr[4];
            #pragma unroll
            for (int ni = 0; ni < 4; ++ni) {
                int col = 16 * ni + n + dx;
                bfr[ni] = *(const half8*)&act[((dy * 66 + col) * 5 + q) * 8];
            }
            #pragma unroll
            for (int g = 0; g < 4; ++g)
                #pragma unroll
                for (int ni = 0; ni < 4; ++ni)
                    acc[g][ni] = __builtin_amdgcn_mfma_f32_16x16x32_f16(
                        wfr[g], bfr[ni], acc[g][ni], 0, 0, 0);
        }
    }

    if (XS) {
        if (NH == 0) __syncthreads();        // only barrier needed when no chunks ran
        const _Float16* wbase = wr + (NH * 9) * 8192 + (hg * 16 + n) * 32 + q * 8;
        half8 wfr[4];
        #pragma unroll
        for (int g = 0; g < 4; ++g)
            wfr[g] = *(const half8*)(wbase + g * 2048);
        half8 bfr[4];
        #pragma unroll
        for (int ni = 0; ni < 4; ++ni)
            bfr[ni] = *(const half8*)&extra[((16 * ni + n) * 5 + q) * 8];
        #pragma unroll
        for (int g = 0; g < 4; ++g)
            #pragma unroll
            for (int ni = 0; ni < 4; ++ni)
                acc[g][ni] = __builtin_amdgcn_mfma_f32_16x16x32_f16(
                    wfr[g], bfr[ni], acc[g][ni], 0, 0, 0);
    }

    // Epilogue: lane holds gates for h = hg*16+q*4+r, pixel row rb, col 16*ni+n
    const int hb = hg * 16 + q * 4;
    floatx4 bi = *(const floatx4*)&bias[hb];
    floatx4 bf = *(const floatx4*)&bias[64 + hb];
    floatx4 bo = *(const floatx4*)&bias[128 + hb];
    floatx4 bg = *(const floatx4*)&bias[192 + hb];
    float* hd = (float*)extra;               // HEAD scratch: [64 col][17]
    float whv[4];
    if (HEAD) {
        #pragma unroll
        for (int r = 0; r < 4; ++r) whv[r] = wh[hb + r];
    }
    #pragma unroll
    for (int ni = 0; ni < 4; ++ni) {
        int col = 16 * ni + n;
        int cidx = ((b * HWSZ + rb * IMW + col) << 6) + hb;      // 32-bit offset
        floatx4 cold;
        if (CLOAD) cold = *(const floatx4*)(cpix + cidx);
        else       cold = (floatx4){0.f, 0.f, 0.f, 0.f};
        floatx4 cnew;
        half4 hv;
        #pragma unroll
        for (int r = 0; r < 4; ++r) {
            float zi = acc[0][ni][r] + bi[r];
            float zf = acc[1][ni][r] + bf[r];
            float zo = acc[2][ni][r] + bo[r];
            float zg = acc[3][ni][r] + bg[r];
            float cn = CLOAD ? fmaf(sigmoidf_(zf), cold[r], sigmoidf_(zi) * tanhf_(zg))
                             : sigmoidf_(zi) * tanhf_(zg);
            cnew[r] = cn;
            hv[r] = (_Float16)(sigmoidf_(zo) * tanhf_(cn));
        }
        if (HEAD) {
            // partial head sum over this lane's 4 hids (f16-rounded h, same as R14 path)
            float p = 0.f;
            #pragma unroll
            for (int r = 0; r < 4; ++r) p = fmaf((float)hv[r], whv[r], p);
            hd[col * 17 + (hg * 4 + q)] = p;
        } else {
            *(floatx4*)(cpix + cidx) = cnew;
            int hidx = (((b * PADW + rb + 1) * PADW + col + 1) << 6) + hb;
            *(half4*)(hpad + hidx) = hv;
        }
    }
    if (HEAD) {
        __syncthreads();
        if (tid < 64) {
            float s = bh[0];
            #pragma unroll
            for (int j = 0; j < 16; ++j) s += hd[tid * 17 + j];
            outp[b * HWSZ + rb * IMW + tid] = fmaxf(s, 0.f);
        }
    }
}

// ZMODE: 0 = role0 (L1) only, 1 = role1 (L0) only, 2 = both via blockIdx.z.
template<int NH1, bool C1, bool HEAD1, int NH0, bool XS0, bool C0, int ZMODE>
__global__ __launch_bounds__(256, 4) void fused_step(
    const _Float16* __restrict__ a1, const _Float16* __restrict__ b1,
    _Float16* __restrict__ h1o, float* __restrict__ c1p,
    const _Float16* __restrict__ w1r, const float* __restrict__ bias1,
    const _Float16* __restrict__ a0, const float* __restrict__ x0,
    _Float16* __restrict__ h0o, float* __restrict__ c0p,
    const _Float16* __restrict__ w0r, const float* __restrict__ bias0,
    const float* __restrict__ wh, const float* __restrict__ bh,
    float* __restrict__ outp)
{
    __shared__ __align__(16) _Float16 act[198 * 5 * 8];   // 15.8 KB
    __shared__ __align__(16) _Float16 extra[64 * 5 * 8];  // 10 KB: x-slab / head scratch
    const int tid = threadIdx.x;
    const int rb = blockIdx.x, b = blockIdx.y;
    const int role = (ZMODE == 2) ? (int)blockIdx.z : ZMODE;
    if (ZMODE != 1 && role == 0)
        lstm_body<NH1, false, C1, HEAD1>(a1, b1, nullptr, h1o, c1p, w1r, bias1,
                                         wh, bh, outp, act, extra, tid, rb, b);
    else
        lstm_body<NH0, XS0, C0, false>(a0, nullptr, x0, h0o, c0p, w0r, bias0,
                                       nullptr, nullptr, nullptr, act, extra, tid, rb, b);
}

extern "C" void kernel_launch(void* const* d_in, const int* in_sizes, int n_in,
                              void* d_out, int out_size, void* d_ws, size_t ws_size,
                              hipStream_t stream) {
    const float* x  = (const float*)d_in[0];
    const float* w0 = (const float*)d_in[1];
    const float* b0 = (const float*)d_in[2];
    const float* w1 = (const float*)d_in[3];
    const float* b1 = (const float*)d_in[4];
    const float* wh = (const float*)d_in[5];
    const float* bh = (const float*)d_in[6];
    float* out = (float*)d_out;

    const size_t HPAD = (size_t)BATCH * PADW * PADW * 64;  // 4,460,544 halves
    const size_t CBUF = (size_t)BATCH * HWSZ * 64;         // 4,194,304 floats
    _Float16* hp  = (_Float16*)d_ws;
    _Float16* h0a = hp;
    _Float16* h0b = hp + HPAD;
    _Float16* h1a = hp + 2 * HPAD;
    _Float16* h1b = hp + 3 * HPAD;
    float* cbase = (float*)(hp + 4 * HPAD);
    float* c0 = cbase;
    float* c1 = cbase + CBUF;
    _Float16* wr0 = (_Float16*)(cbase + 2 * CBUF);   // 19*8192 halves
    _Float16* wr1 = wr0 + (size_t)19 * 8192;         // 36*8192 halves

    // Only h BORDERS need zeroing (interiors & c are written before read).
    border_zero<<<1040, 256, 0, stream>>>(hp);
    repack_w0<<<608, 256, 0, stream>>>(w0, wr0);
    repack_w1<<<1152, 256, 0, stream>>>(w1, wr1);

    _Float16* h0buf[2] = {h0a, h0b};
    _Float16* h1buf[2] = {h1a, h1b};
    dim3 block(256);

    // D0 = L0(0): h0(-1)=0 -> x-slab only (NH=0), c0(-1)=0 -> no c load.
    fused_step<0, false, false, 0, true, false, 1><<<dim3(64, BATCH, 1), block, 0, stream>>>(
        nullptr, nullptr, nullptr, nullptr, nullptr, nullptr,
        nullptr, x, h0buf[1], c0, wr0 + (size_t)18 * 8192, b0,
        nullptr, nullptr, nullptr);

    // D1 (t=1): role0 = L1(0): h1(-1)=0 -> NH=2, no c1 load; role1 = L0(1) full.
    fused_step<2, false, false, 2, true, true, 2><<<dim3(64, BATCH, 2), block, 0, stream>>>(
        h0buf[1], nullptr, h1buf[1], c1, wr1, b1,
        h0buf[1], x + (size_t)HWSZ, h0buf[0], c0, wr0, b0,
        nullptr, nullptr, nullptr);

    // steady t=2..15: role0 = L1(t-1) full; role1 = L0(t) full.
    for (int t = 2; t < TSTEPS; ++t) {
        fused_step<4, true, false, 2, true, true, 2><<<dim3(64, BATCH, 2), block, 0, stream>>>(
            h0buf[t & 1], h1buf[(t - 1) & 1], h1buf[t & 1], c1, wr1, b1,
            h0buf[t & 1], x + (size_t)t * HWSZ, h0buf[(t + 1) & 1], c0, wr0, b0,
            nullptr, nullptr, nullptr);
    }

    // final: L1(15) + fused head: reads h0new(15)=h0buf[0], h1(14)=h1buf[1];
    // writes ONLY the head output (h1/c1 stores skipped — nothing reads them).
    fused_step<4, true, true, 0, false, false, 0><<<dim3(64, BATCH, 1), block, 0, stream>>>(
        h0buf[0], h1buf[1], nullptr, c1, wr1, b1,
        nullptr, nullptr, nullptr, nullptr, nullptr, nullptr,
        wh, bh, out);
}

// Round 16
// 1401.467 us; speedup vs baseline: 5.9083x; 1.0672x over previous
//
#include <hip/hip_runtime.h>

#define IMH 64
#define IMW 64
#define HWSZ 4096
#define BATCH 16
#define TSTEPS 16
#define PADW 66

typedef _Float16 half8 __attribute__((ext_vector_type(8)));
typedef _Float16 half4 __attribute__((ext_vector_type(4)));
typedef float floatx4 __attribute__((ext_vector_type(4)));
typedef int intx4 __attribute__((ext_vector_type(4)));

__device__ __forceinline__ float sigmoidf_(float x) { return 1.f / (1.f + __expf(-x)); }
__device__ __forceinline__ float tanhf_(float x) { return 1.f - 2.f / (1.f + __expf(2.f * x)); }

// layer1 weights: 36 slabs wr[gt][m][k32]; m=(g*4+hg)*16+i -> out=g*64+hg*16+i; ci=chunk*32+k.
__global__ void repack_w1(const float* __restrict__ w, _Float16* __restrict__ wr) {
    int total = 36 * 8192;
    for (int idx = blockIdx.x * blockDim.x + threadIdx.x; idx < total;
         idx += gridDim.x * blockDim.x) {
        int k = idx & 31;
        int m = (idx >> 5) & 255;
        int gt = idx >> 13;
        int chunk = gt / 9, tap = gt - chunk * 9;
        int g = m >> 6, hg = (m >> 4) & 3, i = m & 15;
        int out = g * 64 + hg * 16 + i;
        int ci = chunk * 32 + k;
        wr[idx] = (_Float16)w[(out * 128 + ci) * 9 + tap];
    }
}

// layer0 weights: 18 h-slabs (ci = chunk*32+k+1) + 1 x-slab (K-dim = tap: A[m][k]=w_x[out][k], k<9).
__global__ void repack_w0(const float* __restrict__ w, _Float16* __restrict__ wr) {
    int total = 19 * 8192;
    for (int idx = blockIdx.x * blockDim.x + threadIdx.x; idx < total;
         idx += gridDim.x * blockDim.x) {
        int k = idx & 31;
        int m = (idx >> 5) & 255;
        int gt = idx >> 13;
        int g = m >> 6, hg = (m >> 4) & 3, i = m & 15;
        int out = g * 64 + hg * 16 + i;
        float v = 0.f;
        if (gt < 18) {
            int chunk = gt / 9, tap = gt - chunk * 9;
            v = w[(out * 65 + (chunk * 32 + k + 1)) * 9 + tap];
        } else if (k < 9) {
            v = w[(out * 65 + 0) * 9 + k];   // x-plane, tap k
        }
        wr[idx] = (_Float16)v;
    }
}

// zero ONLY the halo border ring of the 4 contiguous h buffers.
__global__ void border_zero(_Float16* hp) {
    const int total = 4 * BATCH * 260 * 16;          // units of half4
    int idx = blockIdx.x * blockDim.x + threadIdx.x;
    if (idx >= total) return;
    int u = idx & 15;
    int t = idx >> 4;
    int e = t % 260; t /= 260;
    int b = t & 15;
    int buf = t >> 4;
    int py, px;
    if (e < 66)       { py = 0;       px = e; }
    else if (e < 132) { py = 65;      px = e - 66; }
    else if (e < 196) { py = e - 131; px = 0; }
    else              { py = e - 195; px = 65; }
    _Float16* p = hp + (size_t)buf * (BATCH * PADW * PADW * 64)
                + (((b * PADW + py) * PADW + px) << 6) + u * 4;
    *(half4*)p = (half4){(_Float16)0.f, (_Float16)0.f, (_Float16)0.f, (_Float16)0.f};
}

// ---- champion block structure: 256 thr = 4 waves = 4 hid-groups,
// ---- ONE image row x 64 cols, wave tile M=64 x N=64, VGPR 64 + AGPR 64 (locked).

__device__ __forceinline__ void stage_h(const _Float16* __restrict__ buf, int halfsel,
                                        _Float16* __restrict__ act, int tid, int b, int rb) {
    const int rowbase = (b * PADW + rb) * PADW;
    for (int t = tid; t < 792; t += 256) {
        int pix = t >> 2, sl = t & 3;
        int r = pix / 66, cs = pix - r * 66;
        int gofs = ((rowbase + r * PADW + cs) << 6) + (halfsel << 5) + (sl << 3);
        *(intx4*)&act[(pix * 5 + sl) * 8] = *(const intx4*)(buf + gofs);
    }
}

// NH = # of 32-ch h chunks; XS = append x-slab (taps in K-dim, staged in extra at
// kernel start — chunk-loop barriers order it); CLOAD = load previous c;
// HEAD = fuse 1x1-conv+ReLU head, skip h/c stores (final dispatch only).
template<int NH, bool XS, bool CLOAD, bool HEAD>
__device__ __forceinline__ void lstm_body(
    const _Float16* __restrict__ srcA,    // h chunks 0-1
    const _Float16* __restrict__ srcB,    // h chunks 2-3
    const float* __restrict__ xsrc,       // layer0 x_t
    _Float16* __restrict__ hpad,          // out h [B][66][66][64]
    float* __restrict__ cpix,             // in-place c [B][4096][64]
    const _Float16* __restrict__ wr,      // [NH*9(+1)][256][32]
    const float* __restrict__ bias,       // [256]
    const float* __restrict__ wh,         // [64]  (HEAD)
    const float* __restrict__ bh,         // [1]   (HEAD)
    float* __restrict__ outp,             // [B][64][64] (HEAD)
    _Float16* __restrict__ act,           // LDS, 198*5*8 halves
    _Float16* __restrict__ extra,         // LDS, 5120 halves: x-slab (XS) / head scratch
    int tid, int rb, int b)
{
    const int lane = tid & 63;
    const int n = lane & 15, q = lane >> 4;
    const int hg = tid >> 6;

    if (XS) {
        // x-slab staging at block start: B[k=tap][col], col=pix, k=sl*8+j (k>=9 zero)
        int pix = tid >> 2, sl = tid & 3;
        half8 hv;
        #pragma unroll
        for (int j = 0; j < 8; ++j) hv[j] = (_Float16)0.f;
        const float* xb = xsrc + b * (TSTEPS * HWSZ);
        if (sl == 0) {
            #pragma unroll
            for (int j = 0; j < 8; ++j) {
                int gy = rb - 1 + j / 3, gx = pix - 1 + j % 3;
                if (gy >= 0 && gy < IMH && gx >= 0 && gx < IMW)
                    hv[j] = (_Float16)xb[gy * IMW + gx];
            }
        } else if (sl == 1) {
            int gy = rb + 1, gx = pix + 1;               // tap 8: dy=2,dx=2
            if (gy < IMH && gx < IMW)
                hv[0] = (_Float16)xb[gy * IMW + gx];
        }
        *(half8*)&extra[(pix * 5 + sl) * 8] = hv;
    }

    floatx4 acc[4][4];
    #pragma unroll
    for (int g = 0; g < 4; ++g)
        #pragma unroll
        for (int i = 0; i < 4; ++i) acc[g][i] = (floatx4){0.f, 0.f, 0.f, 0.f};

    #pragma unroll
    for (int chunk = 0; chunk < NH; ++chunk) {
        __syncthreads();                     // prev act readers done (orders extra too)
        stage_h((chunk < 2) ? srcA : srcB, chunk & 1, act, tid, b, rb);
        __syncthreads();                     // writes visible
        const _Float16* wbase = wr + (chunk * 9) * 8192 + (hg * 16 + n) * 32 + q * 8;
        #pragma unroll
        for (int tap = 0; tap < 9; ++tap) {
            half8 wfr[4];
            #pragma unroll
            for (int g = 0; g < 4; ++g)
                wfr[g] = *(const half8*)(wbase + tap * 8192 + g * 2048);
            const int dy = tap / 3, dx = tap - dy * 3;
            half8 bfr[4];
            #pragma unroll
            for (int ni = 0; ni < 4; ++ni) {
                int col = 16 * ni + n + dx;
                bfr[ni] = *(const half8*)&act[((dy * 66 + col) * 5 + q) * 8];
            }
            #pragma unroll
            for (int g = 0; g < 4; ++g)
                #pragma unroll
                for (int ni = 0; ni < 4; ++ni)
                    acc[g][ni] = __builtin_amdgcn_mfma_f32_16x16x32_f16(
                        wfr[g], bfr[ni], acc[g][ni], 0, 0, 0);
        }
    }

    if (XS) {
        if (NH == 0) __syncthreads();        // only barrier needed when no chunks ran
        const _Float16* wbase = wr + (NH * 9) * 8192 + (hg * 16 + n) * 32 + q * 8;
        half8 wfr[4];
        #pragma unroll
        for (int g = 0; g < 4; ++g)
            wfr[g] = *(const half8*)(wbase + g * 2048);
        half8 bfr[4];
        #pragma unroll
        for (int ni = 0; ni < 4; ++ni)
            bfr[ni] = *(const half8*)&extra[((16 * ni + n) * 5 + q) * 8];
        #pragma unroll
        for (int g = 0; g < 4; ++g)
            #pragma unroll
            for (int ni = 0; ni < 4; ++ni)
                acc[g][ni] = __builtin_amdgcn_mfma_f32_16x16x32_f16(
                    wfr[g], bfr[ni], acc[g][ni], 0, 0, 0);
    }

    // Epilogue: lane holds gates for h = hg*16+q*4+r, pixel row rb, col 16*ni+n
    const int hb = hg * 16 + q * 4;
    floatx4 bi = *(const floatx4*)&bias[hb];
    floatx4 bf = *(const floatx4*)&bias[64 + hb];
    floatx4 bo = *(const floatx4*)&bias[128 + hb];
    floatx4 bg = *(const floatx4*)&bias[192 + hb];
    float* hd = (float*)extra;               // HEAD scratch: [64 col][17]
    float whv[4];
    if (HEAD) {
        #pragma unroll
        for (int r = 0; r < 4; ++r) whv[r] = wh[hb + r];
    }
    #pragma unroll
    for (int ni = 0; ni < 4; ++ni) {
        int col = 16 * ni + n;
        int cidx = ((b * HWSZ + rb * IMW + col) << 6) + hb;      // 32-bit offset
        floatx4 cold;
        if (CLOAD) cold = *(const floatx4*)(cpix + cidx);
        else       cold = (floatx4){0.f, 0.f, 0.f, 0.f};
        floatx4 cnew;
        half4 hv;
        #pragma unroll
        for (int r = 0; r < 4; ++r) {
            float zi = acc[0][ni][r] + bi[r];
            float zf = acc[1][ni][r] + bf[r];
            float zo = acc[2][ni][r] + bo[r];
            float zg = acc[3][ni][r] + bg[r];
            float cn = CLOAD ? fmaf(sigmoidf_(zf), cold[r], sigmoidf_(zi) * tanhf_(zg))
                             : sigmoidf_(zi) * tanhf_(zg);
            cnew[r] = cn;
            hv[r] = (_Float16)(sigmoidf_(zo) * tanhf_(cn));
        }
        if (HEAD) {
            // partial head sum over this lane's 4 hids (f16-rounded h, same numerics)
            float p = 0.f;
            #pragma unroll
            for (int r = 0; r < 4; ++r) p = fmaf((float)hv[r], whv[r], p);
            hd[col * 17 + (hg * 4 + q)] = p;
        } else {
            *(floatx4*)(cpix + cidx) = cnew;
            int hidx = (((b * PADW + rb + 1) * PADW + col + 1) << 6) + hb;
            *(half4*)(hpad + hidx) = hv;
        }
    }
    if (HEAD) {
        __syncthreads();
        if (tid < 64) {
            float s = bh[0];
            #pragma unroll
            for (int j = 0; j < 16; ++j) s += hd[tid * 17 + j];
            outp[b * HWSZ + rb * IMW + tid] = fmaxf(s, 0.f);
        }
    }
}

// ZMODE: 0 = role0 (L1) only, 1 = role1 (L0) only, 2 = both via blockIdx.z.
template<int NH1, bool C1, bool HEAD1, int NH0, bool XS0, bool C0, int ZMODE>
__global__ __launch_bounds__(256, 4) void fused_step(
    const _Float16* __restrict__ a1, const _Float16* __restrict__ b1,
    _Float16* __restrict__ h1o, float* __restrict__ c1p,
    const _Float16* __restrict__ w1r, const float* __restrict__ bias1,
    const _Float16* __restrict__ a0, const float* __restrict__ x0,
    _Float16* __restrict__ h0o, float* __restrict__ c0p,
    const _Float16* __restrict__ w0r, const float* __restrict__ bias0,
    const float* __restrict__ wh, const float* __restrict__ bh,
    float* __restrict__ outp)
{
    __shared__ __align__(16) _Float16 act[198 * 5 * 8];   // 15.8 KB
    __shared__ __align__(16) _Float16 extra[64 * 5 * 8];  // 10 KB: x-slab / head scratch
    const int tid = threadIdx.x;
    // XCD-aware row swizzle: under the id%8 XCD heuristic, one XCD handles a
    // contiguous 8-row band (all batches, both roles) -> halo + h0new + c rows
    // stay XCD-L2-local. Pure permutation: correctness-neutral.
    const int rb = ((blockIdx.x & 7) << 3) | (blockIdx.x >> 3);
    const int b = blockIdx.y;
    const int role = (ZMODE == 2) ? (int)blockIdx.z : ZMODE;
    if (ZMODE != 1 && role == 0)
        lstm_body<NH1, false, C1, HEAD1>(a1, b1, nullptr, h1o, c1p, w1r, bias1,
                                         wh, bh, outp, act, extra, tid, rb, b);
    else
        lstm_body<NH0, XS0, C0, false>(a0, nullptr, x0, h0o, c0p, w0r, bias0,
                                       nullptr, nullptr, nullptr, act, extra, tid, rb, b);
}

extern "C" void kernel_launch(void* const* d_in, const int* in_sizes, int n_in,
                              void* d_out, int out_size, void* d_ws, size_t ws_size,
                              hipStream_t stream) {
    const float* x  = (const float*)d_in[0];
    const float* w0 = (const float*)d_in[1];
    const float* b0 = (const float*)d_in[2];
    const float* w1 = (const float*)d_in[3];
    const float* b1 = (const float*)d_in[4];
    const float* wh = (const float*)d_in[5];
    const float* bh = (const float*)d_in[6];
    float* out = (float*)d_out;

    const size_t HPAD = (size_t)BATCH * PADW * PADW * 64;  // 4,460,544 halves
    const size_t CBUF = (size_t)BATCH * HWSZ * 64;         // 4,194,304 floats
    _Float16* hp  = (_Float16*)d_ws;
    _Float16* h0a = hp;
    _Float16* h0b = hp + HPAD;
    _Float16* h1a = hp + 2 * HPAD;
    _Float16* h1b = hp + 3 * HPAD;
    float* cbase = (float*)(hp + 4 * HPAD);
    float* c0 = cbase;
    float* c1 = cbase + CBUF;
    _Float16* wr0 = (_Float16*)(cbase + 2 * CBUF);   // 19*8192 halves
    _Float16* wr1 = wr0 + (size_t)19 * 8192;         // 36*8192 halves

    // Only h BORDERS need zeroing (interiors & c are written before read).
    border_zero<<<1040, 256, 0, stream>>>(hp);
    repack_w0<<<608, 256, 0, stream>>>(w0, wr0);
    repack_w1<<<1152, 256, 0, stream>>>(w1, wr1);

    _Float16* h0buf[2] = {h0a, h0b};
    _Float16* h1buf[2] = {h1a, h1b};
    dim3 block(256);

    // D0 = L0(0): h0(-1)=0 -> x-slab only (NH=0), c0(-1)=0 -> no c load.
    fused_step<0, false, false, 0, true, false, 1><<<dim3(64, BATCH, 1), block, 0, stream>>>(
        nullptr, nullptr, nullptr, nullptr, nullptr, nullptr,
        nullptr, x, h0buf[1], c0, wr0 + (size_t)18 * 8192, b0,
        nullptr, nullptr, nullptr);

    // D1 (t=1): role0 = L1(0): h1(-1)=0 -> NH=2, no c1 load; role1 = L0(1) full.
    fused_step<2, false, false, 2, true, true, 2><<<dim3(64, BATCH, 2), block, 0, stream>>>(
        h0buf[1], nullptr, h1buf[1], c1, wr1, b1,
        h0buf[1], x + (size_t)HWSZ, h0buf[0], c0, wr0, b0,
        nullptr, nullptr, nullptr);

    // steady t=2..15: role0 = L1(t-1) full; role1 = L0(t) full.
    for (int t = 2; t < TSTEPS; ++t) {
        fused_step<4, true, false, 2, true, true, 2><<<dim3(64, BATCH, 2), block, 0, stream>>>(
            h0buf[t & 1], h1buf[(t - 1) & 1], h1buf[t & 1], c1, wr1, b1,
            h0buf[t & 1], x + (size_t)t * HWSZ, h0buf[(t + 1) & 1], c0, wr0, b0,
            nullptr, nullptr, nullptr);
    }

    // final: L1(15) + fused head: writes ONLY the head output.
    fused_step<4, true, true, 0, false, false, 0><<<dim3(64, BATCH, 1), block, 0, stream>>>(
        h0buf[0], h1buf[1], nullptr, c1, wr1, b1,
        nullptr, nullptr, nullptr, nullptr, nullptr, nullptr,
        wh, bh, out);
}

// Round 17
// 1337.096 us; speedup vs baseline: 6.1928x; 1.0481x over previous
//
#include <hip/hip_runtime.h>

#define IMH 64
#define IMW 64
#define HWSZ 4096
#define BATCH 16
#define TSTEPS 16
#define PADW 66

typedef _Float16 half8 __attribute__((ext_vector_type(8)));
typedef _Float16 half4 __attribute__((ext_vector_type(4)));
typedef float floatx4 __attribute__((ext_vector_type(4)));
typedef int intx4 __attribute__((ext_vector_type(4)));

__device__ __forceinline__ float sigmoidf_(float x) { return 1.f / (1.f + __expf(-x)); }
__device__ __forceinline__ float tanhf_(float x) { return 1.f - 2.f / (1.f + __expf(2.f * x)); }

// layer1 weights: 36 slabs wr[gt][m][k32]; m=(g*4+hg)*16+i -> out=g*64+hg*16+i; ci=chunk*32+k.
__global__ void repack_w1(const float* __restrict__ w, _Float16* __restrict__ wr) {
    int total = 36 * 8192;
    for (int idx = blockIdx.x * blockDim.x + threadIdx.x; idx < total;
         idx += gridDim.x * blockDim.x) {
        int k = idx & 31;
        int m = (idx >> 5) & 255;
        int gt = idx >> 13;
        int chunk = gt / 9, tap = gt - chunk * 9;
        int g = m >> 6, hg = (m >> 4) & 3, i = m & 15;
        int out = g * 64 + hg * 16 + i;
        int ci = chunk * 32 + k;
        wr[idx] = (_Float16)w[(out * 128 + ci) * 9 + tap];
    }
}

// layer0 weights: 18 h-slabs (ci = chunk*32+k+1) + 1 x-slab (K-dim = tap: A[m][k]=w_x[out][k], k<9).
__global__ void repack_w0(const float* __restrict__ w, _Float16* __restrict__ wr) {
    int total = 19 * 8192;
    for (int idx = blockIdx.x * blockDim.x + threadIdx.x; idx < total;
         idx += gridDim.x * blockDim.x) {
        int k = idx & 31;
        int m = (idx >> 5) & 255;
        int gt = idx >> 13;
        int g = m >> 6, hg = (m >> 4) & 3, i = m & 15;
        int out = g * 64 + hg * 16 + i;
        float v = 0.f;
        if (gt < 18) {
            int chunk = gt / 9, tap = gt - chunk * 9;
            v = w[(out * 65 + (chunk * 32 + k + 1)) * 9 + tap];
        } else if (k < 9) {
            v = w[(out * 65 + 0) * 9 + k];   // x-plane, tap k
        }
        wr[idx] = (_Float16)v;
    }
}

// zero ONLY the halo border ring of the 4 contiguous h buffers.
__global__ void border_zero(_Float16* hp) {
    const int total = 4 * BATCH * 260 * 16;          // units of half4
    int idx = blockIdx.x * blockDim.x + threadIdx.x;
    if (idx >= total) return;
    int u = idx & 15;
    int t = idx >> 4;
    int e = t % 260; t /= 260;
    int b = t & 15;
    int buf = t >> 4;
    int py, px;
    if (e < 66)       { py = 0;       px = e; }
    else if (e < 132) { py = 65;      px = e - 66; }
    else if (e < 196) { py = e - 131; px = 0; }
    else              { py = e - 195; px = 65; }
    _Float16* p = hp + (size_t)buf * (BATCH * PADW * PADW * 64)
                + (((b * PADW + py) * PADW + px) << 6) + u * 4;
    *(half4*)p = (half4){(_Float16)0.f, (_Float16)0.f, (_Float16)0.f, (_Float16)0.f};
}

// ---- champion block structure: 256 thr = 4 waves = 4 hid-groups,
// ---- ONE image row x 64 cols, wave tile M=64 x N=64.
// ---- R17: __launch_bounds__(256,3) — ~170-reg/wave budget so the compiler can
// ---- software-pipeline the tap loop (hoist next-tap wfr/bfr across MFMAs);
// ---- measured occupancy was already ~3 waves/SIMD at the (256,4) bound.

__device__ __forceinline__ void stage_h(const _Float16* __restrict__ buf, int halfsel,
                                        _Float16* __restrict__ act, int tid, int b, int rb) {
    const int rowbase = (b * PADW + rb) * PADW;
    for (int t = tid; t < 792; t += 256) {
        int pix = t >> 2, sl = t & 3;
        int r = pix / 66, cs = pix - r * 66;
        int gofs = ((rowbase + r * PADW + cs) << 6) + (halfsel << 5) + (sl << 3);
        *(intx4*)&act[(pix * 5 + sl) * 8] = *(const intx4*)(buf + gofs);
    }
}

// NH = # of 32-ch h chunks; XS = append x-slab (taps in K-dim, staged in extra at
// kernel start — chunk-loop barriers order it); CLOAD = load previous c;
// HEAD = fuse 1x1-conv+ReLU head, skip h/c stores (final dispatch only).
template<int NH, bool XS, bool CLOAD, bool HEAD>
__device__ __forceinline__ void lstm_body(
    const _Float16* __restrict__ srcA,    // h chunks 0-1
    const _Float16* __restrict__ srcB,    // h chunks 2-3
    const float* __restrict__ xsrc,       // layer0 x_t
    _Float16* __restrict__ hpad,          // out h [B][66][66][64]
    float* __restrict__ cpix,             // in-place c [B][4096][64]
    const _Float16* __restrict__ wr,      // [NH*9(+1)][256][32]
    const float* __restrict__ bias,       // [256]
    const float* __restrict__ wh,         // [64]  (HEAD)
    const float* __restrict__ bh,         // [1]   (HEAD)
    float* __restrict__ outp,             // [B][64][64] (HEAD)
    _Float16* __restrict__ act,           // LDS, 198*5*8 halves
    _Float16* __restrict__ extra,         // LDS, 5120 halves: x-slab (XS) / head scratch
    int tid, int rb, int b)
{
    const int lane = tid & 63;
    const int n = lane & 15, q = lane >> 4;
    const int hg = tid >> 6;

    if (XS) {
        // x-slab staging at block start: B[k=tap][col], col=pix, k=sl*8+j (k>=9 zero)
        int pix = tid >> 2, sl = tid & 3;
        half8 hv;
        #pragma unroll
        for (int j = 0; j < 8; ++j) hv[j] = (_Float16)0.f;
        const float* xb = xsrc + b * (TSTEPS * HWSZ);
        if (sl == 0) {
            #pragma unroll
            for (int j = 0; j < 8; ++j) {
                int gy = rb - 1 + j / 3, gx = pix - 1 + j % 3;
                if (gy >= 0 && gy < IMH && gx >= 0 && gx < IMW)
                    hv[j] = (_Float16)xb[gy * IMW + gx];
            }
        } else if (sl == 1) {
            int gy = rb + 1, gx = pix + 1;               // tap 8: dy=2,dx=2
            if (gy < IMH && gx < IMW)
                hv[0] = (_Float16)xb[gy * IMW + gx];
        }
        *(half8*)&extra[(pix * 5 + sl) * 8] = hv;
    }

    floatx4 acc[4][4];
    #pragma unroll
    for (int g = 0; g < 4; ++g)
        #pragma unroll
        for (int i = 0; i < 4; ++i) acc[g][i] = (floatx4){0.f, 0.f, 0.f, 0.f};

    #pragma unroll
    for (int chunk = 0; chunk < NH; ++chunk) {
        __syncthreads();                     // prev act readers done (orders extra too)
        stage_h((chunk < 2) ? srcA : srcB, chunk & 1, act, tid, b, rb);
        __syncthreads();                     // writes visible
        const _Float16* wbase = wr + (chunk * 9) * 8192 + (hg * 16 + n) * 32 + q * 8;
        #pragma unroll
        for (int tap = 0; tap < 9; ++tap) {
            half8 wfr[4];
            #pragma unroll
            for (int g = 0; g < 4; ++g)
                wfr[g] = *(const half8*)(wbase + tap * 8192 + g * 2048);
            const int dy = tap / 3, dx = tap - dy * 3;
            half8 bfr[4];
            #pragma unroll
            for (int ni = 0; ni < 4; ++ni) {
                int col = 16 * ni + n + dx;
                bfr[ni] = *(const half8*)&act[((dy * 66 + col) * 5 + q) * 8];
            }
            #pragma unroll
            for (int g = 0; g < 4; ++g)
                #pragma unroll
                for (int ni = 0; ni < 4; ++ni)
                    acc[g][ni] = __builtin_amdgcn_mfma_f32_16x16x32_f16(
                        wfr[g], bfr[ni], acc[g][ni], 0, 0, 0);
        }
    }

    if (XS) {
        if (NH == 0) __syncthreads();        // only barrier needed when no chunks ran
        const _Float16* wbase = wr + (NH * 9) * 8192 + (hg * 16 + n) * 32 + q * 8;
        half8 wfr[4];
        #pragma unroll
        for (int g = 0; g < 4; ++g)
            wfr[g] = *(const half8*)(wbase + g * 2048);
        half8 bfr[4];
        #pragma unroll
        for (int ni = 0; ni < 4; ++ni)
            bfr[ni] = *(const half8*)&extra[((16 * ni + n) * 5 + q) * 8];
        #pragma unroll
        for (int g = 0; g < 4; ++g)
            #pragma unroll
            for (int ni = 0; ni < 4; ++ni)
                acc[g][ni] = __builtin_amdgcn_mfma_f32_16x16x32_f16(
                    wfr[g], bfr[ni], acc[g][ni], 0, 0, 0);
    }

    // Epilogue: lane holds gates for h = hg*16+q*4+r, pixel row rb, col 16*ni+n
    const int hb = hg * 16 + q * 4;
    floatx4 bi = *(const floatx4*)&bias[hb];
    floatx4 bf = *(const floatx4*)&bias[64 + hb];
    floatx4 bo = *(const floatx4*)&bias[128 + hb];
    floatx4 bg = *(const floatx4*)&bias[192 + hb];
    float* hd = (float*)extra;               // HEAD scratch: [64 col][17]
    float whv[4];
    if (HEAD) {
        #pragma unroll
        for (int r = 0; r < 4; ++r) whv[r] = wh[hb + r];
    }
    #pragma unroll
    for (int ni = 0; ni < 4; ++ni) {
        int col = 16 * ni + n;
        int cidx = ((b * HWSZ + rb * IMW + col) << 6) + hb;      // 32-bit offset
        floatx4 cold;
        if (CLOAD) cold = *(const floatx4*)(cpix + cidx);
        else       cold = (floatx4){0.f, 0.f, 0.f, 0.f};
        floatx4 cnew;
        half4 hv;
        #pragma unroll
        for (int r = 0; r < 4; ++r) {
            float zi = acc[0][ni][r] + bi[r];
            float zf = acc[1][ni][r] + bf[r];
            float zo = acc[2][ni][r] + bo[r];
            float zg = acc[3][ni][r] + bg[r];
            float cn = CLOAD ? fmaf(sigmoidf_(zf), cold[r], sigmoidf_(zi) * tanhf_(zg))
                             : sigmoidf_(zi) * tanhf_(zg);
            cnew[r] = cn;
            hv[r] = (_Float16)(sigmoidf_(zo) * tanhf_(cn));
        }
        if (HEAD) {
            // partial head sum over this lane's 4 hids (f16-rounded h, same numerics)
            float p = 0.f;
            #pragma unroll
            for (int r = 0; r < 4; ++r) p = fmaf((float)hv[r], whv[r], p);
            hd[col * 17 + (hg * 4 + q)] = p;
        } else {
            *(floatx4*)(cpix + cidx) = cnew;
            int hidx = (((b * PADW + rb + 1) * PADW + col + 1) << 6) + hb;
            *(half4*)(hpad + hidx) = hv;
        }
    }
    if (HEAD) {
        __syncthreads();
        if (tid < 64) {
            float s = bh[0];
            #pragma unroll
            for (int j = 0; j < 16; ++j) s += hd[tid * 17 + j];
            outp[b * HWSZ + rb * IMW + tid] = fmaxf(s, 0.f);
        }
    }
}

// ZMODE: 0 = role0 (L1) only, 1 = role1 (L0) only, 2 = both via blockIdx.z.
template<int NH1, bool C1, bool HEAD1, int NH0, bool XS0, bool C0, int ZMODE>
__global__ __launch_bounds__(256, 3) void fused_step(
    const _Float16* __restrict__ a1, const _Float16* __restrict__ b1,
    _Float16* __restrict__ h1o, float* __restrict__ c1p,
    const _Float16* __restrict__ w1r, const float* __restrict__ bias1,
    const _Float16* __restrict__ a0, const float* __restrict__ x0,
    _Float16* __restrict__ h0o, float* __restrict__ c0p,
    const _Float16* __restrict__ w0r, const float* __restrict__ bias0,
    const float* __restrict__ wh, const float* __restrict__ bh,
    float* __restrict__ outp)
{
    __shared__ __align__(16) _Float16 act[198 * 5 * 8];   // 15.8 KB
    __shared__ __align__(16) _Float16 extra[64 * 5 * 8];  // 10 KB: x-slab / head scratch
    const int tid = threadIdx.x;
    // XCD-aware row swizzle: under the id%8 XCD heuristic, one XCD handles a
    // contiguous 8-row band (all batches, both roles) -> halo + h0new + c rows
    // stay XCD-L2-local. Pure permutation: correctness-neutral.
    const int rb = ((blockIdx.x & 7) << 3) | (blockIdx.x >> 3);
    const int b = blockIdx.y;
    const int role = (ZMODE == 2) ? (int)blockIdx.z : ZMODE;
    if (ZMODE != 1 && role == 0)
        lstm_body<NH1, false, C1, HEAD1>(a1, b1, nullptr, h1o, c1p, w1r, bias1,
                                         wh, bh, outp, act, extra, tid, rb, b);
    else
        lstm_body<NH0, XS0, C0, false>(a0, nullptr, x0, h0o, c0p, w0r, bias0,
                                       nullptr, nullptr, nullptr, act, extra, tid, rb, b);
}

extern "C" void kernel_launch(void* const* d_in, const int* in_sizes, int n_in,
                              void* d_out, int out_size, void* d_ws, size_t ws_size,
                              hipStream_t stream) {
    const float* x  = (const float*)d_in[0];
    const float* w0 = (const float*)d_in[1];
    const float* b0 = (const float*)d_in[2];
    const float* w1 = (const float*)d_in[3];
    const float* b1 = (const float*)d_in[4];
    const float* wh = (const float*)d_in[5];
    const float* bh = (const float*)d_in[6];
    float* out = (float*)d_out;

    const size_t HPAD = (size_t)BATCH * PADW * PADW * 64;  // 4,460,544 halves
    const size_t CBUF = (size_t)BATCH * HWSZ * 64;         // 4,194,304 floats
    _Float16* hp  = (_Float16*)d_ws;
    _Float16* h0a = hp;
    _Float16* h0b = hp + HPAD;
    _Float16* h1a = hp + 2 * HPAD;
    _Float16* h1b = hp + 3 * HPAD;
    float* cbase = (float*)(hp + 4 * HPAD);
    float* c0 = cbase;
    float* c1 = cbase + CBUF;
    _Float16* wr0 = (_Float16*)(cbase + 2 * CBUF);   // 19*8192 halves
    _Float16* wr1 = wr0 + (size_t)19 * 8192;         // 36*8192 halves

    // Only h BORDERS need zeroing (interiors & c are written before read).
    border_zero<<<1040, 256, 0, stream>>>(hp);
    repack_w0<<<608, 256, 0, stream>>>(w0, wr0);
    repack_w1<<<1152, 256, 0, stream>>>(w1, wr1);

    _Float16* h0buf[2] = {h0a, h0b};
    _Float16* h1buf[2] = {h1a, h1b};
    dim3 block(256);

    // D0 = L0(0): h0(-1)=0 -> x-slab only (NH=0), c0(-1)=0 -> no c load.
    fused_step<0, false, false, 0, true, false, 1><<<dim3(64, BATCH, 1), block, 0, stream>>>(
        nullptr, nullptr, nullptr, nullptr, nullptr, nullptr,
        nullptr, x, h0buf[1], c0, wr0 + (size_t)18 * 8192, b0,
        nullptr, nullptr, nullptr);

    // D1 (t=1): role0 = L1(0): h1(-1)=0 -> NH=2, no c1 load; role1 = L0(1) full.
    fused_step<2, false, false, 2, true, true, 2><<<dim3(64, BATCH, 2), block, 0, stream>>>(
        h0buf[1], nullptr, h1buf[1], c1, wr1, b1,
        h0buf[1], x + (size_t)HWSZ, h0buf[0], c0, wr0, b0,
        nullptr, nullptr, nullptr);

    // steady t=2..15: role0 = L1(t-1) full; role1 = L0(t) full.
    for (int t = 2; t < TSTEPS; ++t) {
        fused_step<4, true, false, 2, true, true, 2><<<dim3(64, BATCH, 2), block, 0, stream>>>(
            h0buf[t & 1], h1buf[(t - 1) & 1], h1buf[t & 1], c1, wr1, b1,
            h0buf[t & 1], x + (size_t)t * HWSZ, h0buf[(t + 1) & 1], c0, wr0, b0,
            nullptr, nullptr, nullptr);
    }

    // final: L1(15) + fused head: writes ONLY the head output.
    fused_step<4, true, true, 0, false, false, 0><<<dim3(64, BATCH, 1), block, 0, stream>>>(
        h0buf[0], h1buf[1], nullptr, c1, wr1, b1,
        nullptr, nullptr, nullptr, nullptr, nullptr, nullptr,
        wh, bh, out);
}